// Round 2
// baseline (878.034 us; speedup 1.0000x reference)
//
#include <hip/hip_runtime.h>
#include <hip/hip_bf16.h>
#include <math.h>

// Problem constants (from reference)
#define VOC 50000
#define DIM 128
#define B   256
#define CTX 8
#define K   10

#define NVEC (VOC / 4)          // 12500 float4 per one-hot row
#define N_VO  (B)               // 256 rows
#define N_VI  (B * CTX)         // 2048 rows
#define N_NEG (B * K)           // 2560 rows
#define NROW  (N_VO + N_VI + N_NEG)  // 4864 rows

#define FULL_CHUNKS 48          // 48 chunks x 256 float4 = 12288; tail = 212 float4

__device__ __forceinline__ bool any_nz(const float4& v) {
    return (v.x != 0.f) | (v.y != 0.f) | (v.z != 0.f) | (v.w != 0.f);
}

// ---------------------------------------------------------------------------
// Kernel 1: one WAVE per one-hot row. Each chunk = 256 float4 (4 KB), 4 per
// lane at stride 64 (fully coalesced 1 KB/instruction). Software-pipelined:
// prefetch chunk c+1 while evaluating chunk c, wave-uniform early exit via
// __ballot — no __syncthreads anywhere. Expected read ~53% of 973 MB.
// ---------------------------------------------------------------------------
__global__ __launch_bounds__(256) void find_indices(
    const float* __restrict__ vo,
    const float* __restrict__ vi,
    const float* __restrict__ neg,
    int* __restrict__ out_idx)
{
    const int wave = blockIdx.x * 4 + ((int)threadIdx.x >> 6);
    const int lane = (int)threadIdx.x & 63;

    const float* row;
    {
        const int r = wave;
        if (r < N_VO)              row = vo  + (size_t)r * VOC;
        else if (r < N_VO + N_VI)  row = vi  + (size_t)(r - N_VO) * VOC;
        else                       row = neg + (size_t)(r - N_VO - N_VI) * VOC;
    }
    const float4* row4 = (const float4*)row;

    float4 cur[4];
#pragma unroll
    for (int j = 0; j < 4; ++j) cur[j] = row4[j * 64 + lane];

    int base = 0;
    for (int c = 0; c < FULL_CHUNKS; ++c) {
        // prefetch chunk c+1 (bounds-checked only for the tail chunk)
        float4 nxt[4];
        const int nb = base + 256;
        if (c + 1 < FULL_CHUNKS) {
#pragma unroll
            for (int j = 0; j < 4; ++j) nxt[j] = row4[nb + j * 64 + lane];
        } else {
#pragma unroll
            for (int j = 0; j < 4; ++j) {
                const int p = nb + j * 64 + lane;
                nxt[j] = (p < NVEC) ? row4[p] : make_float4(0.f, 0.f, 0.f, 0.f);
            }
        }

        // evaluate chunk c
        const bool pred = any_nz(cur[0]) | any_nz(cur[1]) |
                          any_nz(cur[2]) | any_nz(cur[3]);
        const unsigned long long m = __ballot(pred);
        if (m) {                       // wave-uniform
            if (pred) {                // exactly one lane (one nonzero/row)
                int idx = -1;
#pragma unroll
                for (int j = 0; j < 4; ++j) {
                    const int p = base + j * 64 + lane;
                    if (cur[j].x != 0.f) idx = 4 * p;
                    if (cur[j].y != 0.f) idx = 4 * p + 1;
                    if (cur[j].z != 0.f) idx = 4 * p + 2;
                    if (cur[j].w != 0.f) idx = 4 * p + 3;
                }
                out_idx[wave] = idx;
            }
            return;
        }
#pragma unroll
        for (int j = 0; j < 4; ++j) cur[j] = nxt[j];
        base = nb;
    }

    // tail chunk (base = 12288), already loaded (bounds-checked) into cur
    const bool pred = any_nz(cur[0]) | any_nz(cur[1]) |
                      any_nz(cur[2]) | any_nz(cur[3]);
    if (pred) {
        int idx = -1;
#pragma unroll
        for (int j = 0; j < 4; ++j) {
            const int p = base + j * 64 + lane;
            if (cur[j].x != 0.f) idx = 4 * p;
            if (cur[j].y != 0.f) idx = 4 * p + 1;
            if (cur[j].z != 0.f) idx = 4 * p + 2;
            if (cur[j].w != 0.f) idx = 4 * p + 3;
        }
        out_idx[wave] = idx;
    }
}

// ---------------------------------------------------------------------------
// Kernel 2: per-batch-row loss. One wave (64 threads) per b; thread t owns
// dims t and t+64. 11 wave-shuffle dot reductions per block, then a single
// atomicAdd of -(left+right)/B into d_out[0].
// ---------------------------------------------------------------------------
__device__ __forceinline__ float wave_sum(float v) {
#pragma unroll
    for (int o = 32; o > 0; o >>= 1) v += __shfl_down(v, o);
    return v;   // valid in lane 0
}

__device__ __forceinline__ float log_sigmoid(float x) {
    // stable: min(x,0) - log1p(exp(-|x|))
    return fminf(x, 0.f) - log1pf(expf(-fabsf(x)));
}

__global__ __launch_bounds__(64) void cbow_loss(
    const float* __restrict__ V,
    const float* __restrict__ U,
    const int* __restrict__ idx_all,
    float* __restrict__ out)
{
    const int b = blockIdx.x;     // 0..255
    const int t = threadIdx.x;    // 0..63

    const int* idx_vo  = idx_all;
    const int* idx_vi  = idx_all + N_VO;
    const int* idx_neg = idx_all + N_VO + N_VI;

    const int vo_i = max(idx_vo[b], 0);
    const float v0 = V[(size_t)vo_i * DIM + t];
    const float v1 = V[(size_t)vo_i * DIM + t + 64];

    float e0 = 0.f, e1 = 0.f;
#pragma unroll
    for (int c = 0; c < CTX; ++c) {
        const int u = max(idx_vi[b * CTX + c], 0);
        e0 += U[(size_t)u * DIM + t];
        e1 += U[(size_t)u * DIM + t + 64];
    }
    e0 *= (1.f / CTX);
    e1 *= (1.f / CTX);

    const float dot_pos = wave_sum(v0 * e0 + v1 * e1);

    float right = 0.f;
#pragma unroll
    for (int k = 0; k < K; ++k) {
        const int u = max(idx_neg[b * K + k], 0);
        const float s = wave_sum(v0 * U[(size_t)u * DIM + t] +
                                 v1 * U[(size_t)u * DIM + t + 64]);
        if (t == 0) right += log_sigmoid(-s);
    }

    if (t == 0) {
        const float left = log_sigmoid(dot_pos);
        atomicAdd(out, -(left + right) * (1.f / B));
    }
}

// ---------------------------------------------------------------------------
// Launch
// ---------------------------------------------------------------------------
extern "C" void kernel_launch(void* const* d_in, const int* in_sizes, int n_in,
                              void* d_out, int out_size, void* d_ws, size_t ws_size,
                              hipStream_t stream) {
    const float* vo  = (const float*)d_in[0];   // [B, VOC]
    const float* vi  = (const float*)d_in[1];   // [B, CTX, VOC]
    const float* neg = (const float*)d_in[2];   // [B, K, VOC]
    const float* V   = (const float*)d_in[3];   // [VOC, DIM]
    const float* U   = (const float*)d_in[4];   // [VOC, DIM]
    float* out = (float*)d_out;

    int* idx_ws = (int*)d_ws;                   // NROW ints = 19456 B

    // d_out is poisoned with 0xAA before every timed launch; zero it (async,
    // graph-capture safe).
    hipMemsetAsync(out, 0, sizeof(float), stream);

    // NROW waves, 4 waves (256 threads) per block -> 1216 blocks exactly.
    find_indices<<<NROW / 4, 256, 0, stream>>>(vo, vi, neg, idx_ws);
    cbow_loss<<<B, 64, 0, stream>>>(V, U, idx_ws, out);
}